// Round 1
// baseline (2638.137 us; speedup 1.0000x reference)
//
#include <hip/hip_runtime.h>
#include <math.h>

typedef unsigned short u16;
typedef float f32x4 __attribute__((ext_vector_type(4)));
typedef short bf16x8 __attribute__((ext_vector_type(8)));
typedef unsigned short us4 __attribute__((ext_vector_type(4)));

#define DEVI __device__ __forceinline__

DEVI float bf2f(u16 u) { return __uint_as_float(((unsigned int)u) << 16); }
DEVI u16 f2bf(float f) {
    unsigned int u = __float_as_uint(f);
    u += 0x7fffu + ((u >> 16) & 1u);
    return (u16)(u >> 16);
}

// ---------------------------------------------------------------- embedding
__global__ __launch_bounds__(256) void k_embed(const int* __restrict__ idx,
                                               const float* __restrict__ te,
                                               const float* __restrict__ pe,
                                               float* __restrict__ x) {
    int m = blockIdx.x;            // 0..2047
    int t = m & 127;
    int tok = idx[m];
    const f32x4* a = (const f32x4*)(te + (long)tok * 1024);
    const f32x4* p = (const f32x4*)(pe + (long)t * 1024);
    f32x4* o = (f32x4*)(x + (long)m * 1024);
    o[threadIdx.x] = a[threadIdx.x] + p[threadIdx.x];
}

// ---------------------------------------------------------------- layernorm -> bf16
__global__ __launch_bounds__(256) void k_ln(const float* __restrict__ x,
                                            const float* __restrict__ g,
                                            const float* __restrict__ b,
                                            u16* __restrict__ out) {
    __shared__ float red[8];
    int tid = threadIdx.x, lane = tid & 63, wid = tid >> 6;
    int r = blockIdx.x;
    f32x4 v = ((const f32x4*)(x + (long)r * 1024))[tid];
    float s = v.x + v.y + v.z + v.w;
#pragma unroll
    for (int o2 = 32; o2; o2 >>= 1) s += __shfl_xor(s, o2);
    if (lane == 0) red[wid] = s;
    __syncthreads();
    float mean = (red[0] + red[1] + red[2] + red[3]) * (1.0f / 1024.0f);
    f32x4 d; d.x = v.x - mean; d.y = v.y - mean; d.z = v.z - mean; d.w = v.w - mean;
    float sq = d.x * d.x + d.y * d.y + d.z * d.z + d.w * d.w;
#pragma unroll
    for (int o2 = 32; o2; o2 >>= 1) sq += __shfl_xor(sq, o2);
    if (lane == 0) red[4 + wid] = sq;
    __syncthreads();
    float rstd = rsqrtf((red[4] + red[5] + red[6] + red[7]) * (1.0f / 1024.0f) + 1e-5f);
    f32x4 gg = ((const f32x4*)g)[tid];
    f32x4 bb = ((const f32x4*)b)[tid];
    us4 o4;
    o4.x = f2bf(d.x * rstd * gg.x + bb.x);
    o4.y = f2bf(d.y * rstd * gg.y + bb.y);
    o4.z = f2bf(d.z * rstd * gg.z + bb.z);
    o4.w = f2bf(d.w * rstd * gg.w + bb.w);
    ((us4*)(out + (long)r * 1024))[tid] = o4;
}

// ---------------------------------------------------------------- transpose + cvt f32[K][N] -> bf16[N][K]
DEVI void tr_tile(const float* __restrict__ in, u16* __restrict__ out,
                  int K, int N, int k0, int n0, int tid, float (*tile)[65]) {
    int trow = tid >> 4;             // 0..15
    int tcol = (tid & 15) * 4;       // 0..60
#pragma unroll
    for (int p = 0; p < 4; ++p) {
        int k = k0 + trow + p * 16;
        const float* src = in + (long)k * N + n0 + tcol;
#pragma unroll
        for (int j = 0; j < 4; ++j) {
            int n = n0 + tcol + j;
            tile[trow + p * 16][tcol + j] = (n < N) ? src[j] : 0.0f;
        }
    }
    __syncthreads();
#pragma unroll
    for (int p = 0; p < 4; ++p) {
        int n = n0 + trow + p * 16;
        if (n < N) {
            us4 o4;
#pragma unroll
            for (int j = 0; j < 4; ++j) o4[j] = f2bf(tile[tcol + j][trow + p * 16]);
            *(us4*)(out + (long)n * K + k0 + tcol) = o4;
        }
    }
}

__global__ __launch_bounds__(256) void k_tr_one(const float* __restrict__ in,
                                                u16* __restrict__ out, int K, int N) {
    __shared__ float tile[64][65];
    tr_tile(in, out, K, N, blockIdx.y * 64, blockIdx.x * 64, threadIdx.x, tile);
}

// all 6 per-layer weight matrices in one launch (3072 tile-blocks)
__global__ __launch_bounds__(256) void k_tr_layer(
    const float* __restrict__ wq, const float* __restrict__ wk,
    const float* __restrict__ wv, const float* __restrict__ wp,
    const float* __restrict__ f1, const float* __restrict__ f2,
    u16* __restrict__ oqkv, u16* __restrict__ oproj,
    u16* __restrict__ of1, u16* __restrict__ of2) {
    __shared__ float tile[64][65];
    int id = blockIdx.x;
    const float* in; u16* out; int K, N, txx, tyy;
    if (id < 1024) {
        int t = id >> 8, s2 = id & 255;
        txx = s2 & 15; tyy = s2 >> 4; K = 1024; N = 1024;
        in = (t == 0) ? wq : (t == 1) ? wk : (t == 2) ? wv : wp;
        out = (t == 3) ? oproj : oqkv + (long)t * 1024 * 1024;
    } else if (id < 2048) {
        int s2 = id - 1024;
        txx = s2 & 63; tyy = s2 >> 6; K = 1024; N = 4096; in = f1; out = of1;
    } else {
        int s2 = id - 2048;
        txx = s2 & 15; tyy = s2 >> 4; K = 4096; N = 1024; in = f2; out = of2;
    }
    tr_tile(in, out, K, N, tyy * 64, txx * 64, threadIdx.x, tile);
}

// ---------------------------------------------------------------- GEMM  C[M][N] = A[M][K](bf16) * Bt[N][K](bf16)
// staging: 16B chunks, XOR-swizzled (chunk col ^= row&7) so ds_read_b128 frag reads are conflict-free.
template <int ROWS>
DEVI void stage_tile(const u16* __restrict__ g, long row0, long rowmax, int ld,
                     int col0, char* lds, int tid) {
    constexpr int NCH = ROWS * 8;     // 16B chunks in tile (ROWS x 64 bf16)
#pragma unroll
    for (int p = 0; p < NCH / 256; ++p) {
        int c = tid + p * 256;
        int row = c >> 3;
        int gslot = c & 7;
        int gdata = gslot ^ (row & 7);
        long gr = row0 + row;
        if (gr > rowmax) gr = rowmax;
        const u16* src = g + gr * (long)ld + col0 + gdata * 8;
        char* dst = lds + ((long)((tid & 192) + p * 256)) * 16;   // wave-uniform base; HW adds lane*16
        __builtin_amdgcn_global_load_lds(
            (const __attribute__((address_space(1))) void*)src,
            (__attribute__((address_space(3))) void*)dst, 16, 0, 0);
    }
}

template <int BN, bool OUT_BF16, bool RELU, bool HAS_BIAS, bool HAS_RES>
__global__ __launch_bounds__(256, 2) void k_gemm(
    const u16* __restrict__ A, const u16* __restrict__ Bt,
    const float* __restrict__ bias, const float* __restrict__ res,
    float* __restrict__ Cf, u16* __restrict__ Cb,
    int M, int N, int K, int ldc) {
    constexpr int NR = BN / 32;
    constexpr int ASZ = 128 * 64 * 2;
    constexpr int BSZ = BN * 64 * 2;
    __shared__ __align__(16) char lds[2 * (ASZ + BSZ)];
    int tid = threadIdx.x, lane = tid & 63, wid = tid >> 6;
    int l15 = lane & 15, l4 = lane >> 4;
    int wr = wid >> 1, wc = wid & 1;
    long m0 = (long)blockIdx.y * 128;
    long n0 = (long)blockIdx.x * BN;
    f32x4 acc[4][NR] = {};
    const int nk = K >> 6;

    stage_tile<128>(A, m0, (long)M - 1, K, 0, lds, tid);
    stage_tile<BN>(Bt, n0, (long)N - 1, K, 0, lds + ASZ, tid);
    int cur = 0;
    for (int kt = 0; kt < nk; ++kt) {
        __syncthreads();                       // waits vmcnt(0): stage(cur) landed; prev reads done
        if (kt + 1 < nk) {
            char* nb = lds + (cur ^ 1) * (ASZ + BSZ);
            stage_tile<128>(A, m0, (long)M - 1, K, (kt + 1) << 6, nb, tid);
            stage_tile<BN>(Bt, n0, (long)N - 1, K, (kt + 1) << 6, nb + ASZ, tid);
        }
        const char* ab = lds + cur * (ASZ + BSZ);
        const char* bb = ab + ASZ;
#pragma unroll
        for (int kh = 0; kh < 2; ++kh) {
            bf16x8 af[4], bfv[NR];
#pragma unroll
            for (int mi = 0; mi < 4; ++mi) {
                int row = wr * 64 + mi * 16 + l15;
                int slot = (kh * 4 + l4) ^ (row & 7);
                af[mi] = *(const bf16x8*)(ab + (row * 8 + slot) * 16);
            }
#pragma unroll
            for (int ni = 0; ni < NR; ++ni) {
                int row = wc * (BN / 2) + ni * 16 + l15;
                int slot = (kh * 4 + l4) ^ (row & 7);
                bfv[ni] = *(const bf16x8*)(bb + (row * 8 + slot) * 16);
            }
#pragma unroll
            for (int mi = 0; mi < 4; ++mi)
#pragma unroll
                for (int ni = 0; ni < NR; ++ni)
                    acc[mi][ni] = __builtin_amdgcn_mfma_f32_16x16x32_bf16(
                        af[mi], bfv[ni], acc[mi][ni], 0, 0, 0);
        }
        cur ^= 1;
    }
    // epilogue: C/D layout col=lane&15, row=(lane>>4)*4+reg (verified m89)
#pragma unroll
    for (int ni = 0; ni < NR; ++ni) {
        long n = n0 + wc * (BN / 2) + ni * 16 + l15;
        if (n < N) {
            float bv = HAS_BIAS ? bias[n] : 0.0f;
#pragma unroll
            for (int mi = 0; mi < 4; ++mi) {
#pragma unroll
                for (int j = 0; j < 4; ++j) {
                    long m = m0 + wr * 64 + mi * 16 + l4 * 4 + j;
                    float v = acc[mi][ni][j] + bv;
                    if (HAS_RES) v += res[m * (long)ldc + n];
                    if (RELU) v = fmaxf(v, 0.0f);
                    if (OUT_BF16) Cb[m * (long)ldc + n] = f2bf(v);
                    else Cf[m * (long)ldc + n] = v;
                }
            }
        }
    }
}

// ---------------------------------------------------------------- attention (fp32 math, bf16 LDS tiles)
__global__ __launch_bounds__(256) void k_attn(const float* __restrict__ qkv,
                                              u16* __restrict__ o) {
    __shared__ u16 Ks[128][66];
    __shared__ u16 Vs[128][66];
    __shared__ u16 Qs[32][66];
    __shared__ float ps[4][128];
    int tid = threadIdx.x, lane = tid & 63, wid = tid >> 6;
    int bh = blockIdx.x, b = bh >> 4, h = bh & 15;
    int q0 = blockIdx.y * 32;
    const float* base = qkv + (long)b * 128 * 3072 + h * 64;
    for (int e = tid; e < 128 * 64; e += 256) {
        int r = e >> 6, d = e & 63;
        const float* rp = base + (long)r * 3072;
        Ks[r][d] = f2bf(rp[1024 + d]);
        Vs[r][d] = f2bf(rp[2048 + d]);
    }
    for (int e = tid; e < 32 * 64; e += 256) {
        int r = e >> 6, d = e & 63;
        Qs[r][d] = f2bf(base[(long)(q0 + r) * 3072 + d]);
    }
    __syncthreads();
    const float scale = 0.03125f;    // E^-0.5
    for (int r8 = 0; r8 < 8; ++r8) {
        int rq = wid * 8 + r8;
        int tq = q0 + rq;
        float s0 = 0.f, s1 = 0.f;
        for (int d = 0; d < 64; ++d) {
            float qd = bf2f(Qs[rq][d]);
            s0 += qd * bf2f(Ks[lane][d]);
        }
        if (tq >= 64) {
            for (int d = 0; d < 64; ++d) {
                float qd = bf2f(Qs[rq][d]);
                s1 += qd * bf2f(Ks[lane + 64][d]);
            }
        }
        s0 = (lane <= tq) ? s0 * scale : -INFINITY;
        s1 = (lane + 64 <= tq) ? s1 * scale : -INFINITY;
        float mx = fmaxf(s0, s1);
#pragma unroll
        for (int ofs = 32; ofs; ofs >>= 1) mx = fmaxf(mx, __shfl_xor(mx, ofs));
        float e0 = __expf(s0 - mx), e1 = __expf(s1 - mx);
        float sm = e0 + e1;
#pragma unroll
        for (int ofs = 32; ofs; ofs >>= 1) sm += __shfl_xor(sm, ofs);
        float inv = 1.0f / sm;
        ps[wid][lane] = e0 * inv;
        ps[wid][lane + 64] = e1 * inv;
        asm volatile("s_waitcnt lgkmcnt(0)" ::: "memory");
        float accv = 0.f;
        int nkk = tq + 1;
        for (int j = 0; j < nkk; ++j) accv += ps[wid][j] * bf2f(Vs[j][lane]);
        o[((long)b * 128 + tq) * 1024 + h * 64 + lane] = f2bf(accv);
    }
}

// ---------------------------------------------------------------- loss
__global__ __launch_bounds__(256) void k_loss_rows(const float* __restrict__ logits,
                                                   const int* __restrict__ tgt,
                                                   float* __restrict__ rowloss) {
    __shared__ float rm[4], rs[4];
    int r = blockIdx.x, tid = threadIdx.x, lane = tid & 63, wid = tid >> 6;
    const float* row = logits + (long)r * 50257;
    float m = -INFINITY, s = 0.f;
    for (int i = tid; i < 50257; i += 256) {
        float xv = row[i];
        if (xv > m) { s = s * __expf(m - xv) + 1.0f; m = xv; }
        else s += __expf(xv - m);
    }
#pragma unroll
    for (int ofs = 32; ofs; ofs >>= 1) {
        float m2 = __shfl_xor(m, ofs), s2 = __shfl_xor(s, ofs);
        float nm = fmaxf(m, m2);
        s = s * __expf(m - nm) + s2 * __expf(m2 - nm);
        m = nm;
    }
    if (lane == 0) { rm[wid] = m; rs[wid] = s; }
    __syncthreads();
    if (tid == 0) {
        float M = rm[0], S = rs[0];
        for (int wv = 1; wv < 4; ++wv) {
            float nm = fmaxf(M, rm[wv]);
            S = S * __expf(M - nm) + rs[wv] * __expf(rm[wv] - nm);
            M = nm;
        }
        rowloss[r] = (M + logf(S)) - row[tgt[r]];
    }
}

__global__ __launch_bounds__(256) void k_loss_reduce(const float* __restrict__ rowloss,
                                                     float* __restrict__ out) {
    __shared__ float red[4];
    int tid = threadIdx.x, lane = tid & 63, wid = tid >> 6;
    float s = 0.f;
    for (int i = tid; i < 2048; i += 256) s += rowloss[i];
#pragma unroll
    for (int ofs = 32; ofs; ofs >>= 1) s += __shfl_xor(s, ofs);
    if (lane == 0) red[wid] = s;
    __syncthreads();
    if (tid == 0) out[0] = (red[0] + red[1] + red[2] + red[3]) * (1.0f / 2048.0f);
}

// ---------------------------------------------------------------- host
extern "C" void kernel_launch(void* const* d_in, const int* in_sizes, int n_in,
                              void* d_out, int out_size, void* d_ws, size_t ws_size,
                              hipStream_t stream) {
    (void)in_sizes; (void)n_in; (void)out_size; (void)ws_size;
    const int*   idx     = (const int*)d_in[0];
    const int*   targets = (const int*)d_in[1];
    const float* tok_emb = (const float*)d_in[2];
    const float* pos_emb = (const float*)d_in[3];
    const float* wq      = (const float*)d_in[4];
    const float* wk      = (const float*)d_in[5];
    const float* wv      = (const float*)d_in[6];
    const float* w_proj  = (const float*)d_in[7];
    const float* b_proj  = (const float*)d_in[8];
    const float* ln1_g   = (const float*)d_in[9];
    const float* ln1_b   = (const float*)d_in[10];
    const float* ln2_g   = (const float*)d_in[11];
    const float* ln2_b   = (const float*)d_in[12];
    const float* w_fc1   = (const float*)d_in[13];
    const float* b_fc1   = (const float*)d_in[14];
    const float* w_fc2   = (const float*)d_in[15];
    const float* b_fc2   = (const float*)d_in[16];
    const float* lnf_g   = (const float*)d_in[17];
    const float* lnf_b   = (const float*)d_in[18];
    const float* w_head  = (const float*)d_in[19];
    const float* b_head  = (const float*)d_in[20];
    float* out = (float*)d_out;

    char* w = (char*)d_ws;
    auto alloc = [&](size_t bytes) {
        char* p = w;
        w += (bytes + 255) & ~(size_t)255;
        return p;
    };
    u16*   wT_qkv  = (u16*)alloc(3072L * 1024 * 2);
    u16*   wT_proj = (u16*)alloc(1024L * 1024 * 2);
    u16*   wT_f1   = (u16*)alloc(4096L * 1024 * 2);
    u16*   wT_f2   = (u16*)alloc(1024L * 4096 * 2);
    u16*   wT_head = (u16*)alloc(50257L * 1024 * 2);
    float* x       = (float*)alloc(2048L * 1024 * 4);
    u16*   h_bf    = (u16*)alloc(2048L * 1024 * 2);
    float* qkvb    = (float*)alloc(2048L * 3072 * 4);
    u16*   o_bf    = (u16*)alloc(2048L * 1024 * 2);
    u16*   ff_bf   = (u16*)alloc(2048L * 4096 * 2);
    float* rowloss = (float*)alloc(2048L * 4);

    k_embed<<<2048, 256, 0, stream>>>(idx, tok_emb, pos_emb, x);
    k_tr_one<<<dim3(786, 16), 256, 0, stream>>>(w_head, wT_head, 1024, 50257);

    for (int l = 0; l < 12; ++l) {
        k_tr_layer<<<3072, 256, 0, stream>>>(
            wq + (long)l * 1048576, wk + (long)l * 1048576,
            wv + (long)l * 1048576, w_proj + (long)l * 1048576,
            w_fc1 + (long)l * 4194304, w_fc2 + (long)l * 4194304,
            wT_qkv, wT_proj, wT_f1, wT_f2);
        k_ln<<<2048, 256, 0, stream>>>(x, ln1_g + l * 1024, ln1_b + l * 1024, h_bf);
        k_gemm<64, false, false, false, false><<<dim3(48, 16), 256, 0, stream>>>(
            h_bf, wT_qkv, nullptr, nullptr, qkvb, nullptr, 2048, 3072, 1024, 3072);
        k_attn<<<dim3(256, 4), 256, 0, stream>>>(qkvb, o_bf);
        k_gemm<64, false, false, true, true><<<dim3(16, 16), 256, 0, stream>>>(
            o_bf, wT_proj, b_proj + l * 1024, x, x, nullptr, 2048, 1024, 1024, 1024);
        k_ln<<<2048, 256, 0, stream>>>(x, ln2_g + l * 1024, ln2_b + l * 1024, h_bf);
        k_gemm<128, true, true, true, false><<<dim3(32, 16), 256, 0, stream>>>(
            h_bf, wT_f1, b_fc1 + l * 4096, nullptr, nullptr, ff_bf, 2048, 4096, 1024, 4096);
        k_gemm<64, false, false, true, true><<<dim3(16, 16), 256, 0, stream>>>(
            ff_bf, wT_f2, b_fc2 + l * 1024, x, x, nullptr, 2048, 1024, 4096, 1024);
    }
    k_ln<<<2048, 256, 0, stream>>>(x, lnf_g, lnf_b, h_bf);
    k_gemm<128, false, false, true, false><<<dim3(393, 16), 256, 0, stream>>>(
        h_bf, wT_head, b_head, nullptr, out, nullptr, 2048, 50257, 1024, 50257);
    k_loss_rows<<<2048, 256, 0, stream>>>(out, targets, rowloss);
    k_loss_reduce<<<1, 256, 0, stream>>>(rowloss, out + 102926336L);
}

// Round 2
// 2184.201 us; speedup vs baseline: 1.2078x; 1.2078x over previous
//
#include <hip/hip_runtime.h>
#include <math.h>

typedef unsigned short u16;
typedef float f32x4 __attribute__((ext_vector_type(4)));
typedef short bf16x8 __attribute__((ext_vector_type(8)));
typedef unsigned short us4 __attribute__((ext_vector_type(4)));

#define DEVI __device__ __forceinline__

DEVI float bf2f(u16 u) { return __uint_as_float(((unsigned int)u) << 16); }
DEVI u16 f2bf(float f) {
    unsigned int u = __float_as_uint(f);
    u += 0x7fffu + ((u >> 16) & 1u);
    return (u16)(u >> 16);
}

// ---------------------------------------------------------------- embedding
__global__ __launch_bounds__(256) void k_embed(const int* __restrict__ idx,
                                               const float* __restrict__ te,
                                               const float* __restrict__ pe,
                                               float* __restrict__ x) {
    int m = blockIdx.x;            // 0..2047
    int t = m & 127;
    int tok = idx[m];
    const f32x4* a = (const f32x4*)(te + (long)tok * 1024);
    const f32x4* p = (const f32x4*)(pe + (long)t * 1024);
    f32x4* o = (f32x4*)(x + (long)m * 1024);
    o[threadIdx.x] = a[threadIdx.x] + p[threadIdx.x];
}

// ---------------------------------------------------------------- layernorm -> bf16
__global__ __launch_bounds__(256) void k_ln(const float* __restrict__ x,
                                            const float* __restrict__ g,
                                            const float* __restrict__ b,
                                            u16* __restrict__ out) {
    __shared__ float red[8];
    int tid = threadIdx.x, lane = tid & 63, wid = tid >> 6;
    int r = blockIdx.x;
    f32x4 v = ((const f32x4*)(x + (long)r * 1024))[tid];
    float s = v.x + v.y + v.z + v.w;
#pragma unroll
    for (int o2 = 32; o2; o2 >>= 1) s += __shfl_xor(s, o2);
    if (lane == 0) red[wid] = s;
    __syncthreads();
    float mean = (red[0] + red[1] + red[2] + red[3]) * (1.0f / 1024.0f);
    f32x4 d; d.x = v.x - mean; d.y = v.y - mean; d.z = v.z - mean; d.w = v.w - mean;
    float sq = d.x * d.x + d.y * d.y + d.z * d.z + d.w * d.w;
#pragma unroll
    for (int o2 = 32; o2; o2 >>= 1) sq += __shfl_xor(sq, o2);
    if (lane == 0) red[4 + wid] = sq;
    __syncthreads();
    float rstd = rsqrtf((red[4] + red[5] + red[6] + red[7]) * (1.0f / 1024.0f) + 1e-5f);
    f32x4 gg = ((const f32x4*)g)[tid];
    f32x4 bb = ((const f32x4*)b)[tid];
    us4 o4;
    o4.x = f2bf(d.x * rstd * gg.x + bb.x);
    o4.y = f2bf(d.y * rstd * gg.y + bb.y);
    o4.z = f2bf(d.z * rstd * gg.z + bb.z);
    o4.w = f2bf(d.w * rstd * gg.w + bb.w);
    ((us4*)(out + (long)r * 1024))[tid] = o4;
}

// ---------------------------------------------------------------- transpose + cvt f32[K][N] -> bf16[N][K]
DEVI void tr_tile(const float* __restrict__ in, u16* __restrict__ out,
                  int K, int N, int k0, int n0, int tid, float (*tile)[65]) {
    int trow = tid >> 4;             // 0..15
    int tcol = (tid & 15) * 4;       // 0..60
#pragma unroll
    for (int p = 0; p < 4; ++p) {
        int k = k0 + trow + p * 16;
        const float* src = in + (long)k * N + n0 + tcol;
#pragma unroll
        for (int j = 0; j < 4; ++j) {
            int n = n0 + tcol + j;
            tile[trow + p * 16][tcol + j] = (n < N) ? src[j] : 0.0f;
        }
    }
    __syncthreads();
#pragma unroll
    for (int p = 0; p < 4; ++p) {
        int n = n0 + trow + p * 16;
        if (n < N) {
            us4 o4;
#pragma unroll
            for (int j = 0; j < 4; ++j) o4[j] = f2bf(tile[tcol + j][trow + p * 16]);
            *(us4*)(out + (long)n * K + k0 + tcol) = o4;
        }
    }
}

__global__ __launch_bounds__(256) void k_tr_one(const float* __restrict__ in,
                                                u16* __restrict__ out, int K, int N) {
    __shared__ float tile[64][65];
    tr_tile(in, out, K, N, blockIdx.y * 64, blockIdx.x * 64, threadIdx.x, tile);
}

__global__ __launch_bounds__(256) void k_tr_layer(
    const float* __restrict__ wq, const float* __restrict__ wk,
    const float* __restrict__ wv, const float* __restrict__ wp,
    const float* __restrict__ f1, const float* __restrict__ f2,
    u16* __restrict__ oqkv, u16* __restrict__ oproj,
    u16* __restrict__ of1, u16* __restrict__ of2) {
    __shared__ float tile[64][65];
    int id = blockIdx.x;
    const float* in; u16* out; int K, N, txx, tyy;
    if (id < 1024) {
        int t = id >> 8, s2 = id & 255;
        txx = s2 & 15; tyy = s2 >> 4; K = 1024; N = 1024;
        in = (t == 0) ? wq : (t == 1) ? wk : (t == 2) ? wv : wp;
        out = (t == 3) ? oproj : oqkv + (long)t * 1024 * 1024;
    } else if (id < 2048) {
        int s2 = id - 1024;
        txx = s2 & 63; tyy = s2 >> 6; K = 1024; N = 4096; in = f1; out = of1;
    } else {
        int s2 = id - 2048;
        txx = s2 & 15; tyy = s2 >> 4; K = 4096; N = 1024; in = f2; out = of2;
    }
    tr_tile(in, out, K, N, tyy * 64, txx * 64, threadIdx.x, tile);
}

// ---------------------------------------------------------------- GEMM  C[M][N] = A[M][K](bf16) * Bt[N][K](bf16)
template <int ROWS>
DEVI void stage_tile(const u16* __restrict__ g, long row0, long rowmax, int ld,
                     int col0, char* lds, int tid) {
    constexpr int NCH = ROWS * 8;
#pragma unroll
    for (int p = 0; p < NCH / 256; ++p) {
        int c = tid + p * 256;
        int row = c >> 3;
        int gslot = c & 7;
        int gdata = gslot ^ (row & 7);
        long gr = row0 + row;
        if (gr > rowmax) gr = rowmax;
        const u16* src = g + gr * (long)ld + col0 + gdata * 8;
        char* dst = lds + ((long)((tid & 192) + p * 256)) * 16;
        __builtin_amdgcn_global_load_lds(
            (const __attribute__((address_space(1))) void*)src,
            (__attribute__((address_space(3))) void*)dst, 16, 0, 0);
    }
}

template <int BN, bool OUT_BF16, bool RELU, bool HAS_BIAS, bool HAS_RES, bool GS, bool LP>
__global__ __launch_bounds__(256, 2) void k_gemm(
    const u16* __restrict__ A, const u16* __restrict__ Bt,
    const float* __restrict__ bias, const float* __restrict__ res,
    float* __restrict__ Cf, u16* __restrict__ Cb,
    int M, int N, int K, int ldc, float2* __restrict__ part, int ncb) {
    constexpr int NR = BN / 32;
    constexpr int ASZ = 128 * 64 * 2;
    constexpr int BSZ = BN * 64 * 2;
    __shared__ __align__(16) char lds[2 * (ASZ + BSZ)];
    int tid = threadIdx.x, lane = tid & 63, wid = tid >> 6;
    int l15 = lane & 15, l4 = lane >> 4;
    int wr = wid >> 1, wc = wid & 1;
    int bm = GS ? blockIdx.x : blockIdx.y;
    int bn = GS ? blockIdx.y : blockIdx.x;
    long m0 = (long)bm * 128;
    long n0 = (long)bn * BN;
    f32x4 acc[4][NR] = {};
    const int nk = K >> 6;

    stage_tile<128>(A, m0, (long)M - 1, K, 0, lds, tid);
    stage_tile<BN>(Bt, n0, (long)N - 1, K, 0, lds + ASZ, tid);
    int cur = 0;
    for (int kt = 0; kt < nk; ++kt) {
        __syncthreads();
        if (kt + 1 < nk) {
            char* nb = lds + (cur ^ 1) * (ASZ + BSZ);
            stage_tile<128>(A, m0, (long)M - 1, K, (kt + 1) << 6, nb, tid);
            stage_tile<BN>(Bt, n0, (long)N - 1, K, (kt + 1) << 6, nb + ASZ, tid);
        }
        const char* ab = lds + cur * (ASZ + BSZ);
        const char* bb = ab + ASZ;
#pragma unroll
        for (int kh = 0; kh < 2; ++kh) {
            bf16x8 af[4], bfv[NR];
#pragma unroll
            for (int mi = 0; mi < 4; ++mi) {
                int row = wr * 64 + mi * 16 + l15;
                int slot = (kh * 4 + l4) ^ (row & 7);
                af[mi] = *(const bf16x8*)(ab + (row * 8 + slot) * 16);
            }
#pragma unroll
            for (int ni = 0; ni < NR; ++ni) {
                int row = wc * (BN / 2) + ni * 16 + l15;
                int slot = (kh * 4 + l4) ^ (row & 7);
                bfv[ni] = *(const bf16x8*)(bb + (row * 8 + slot) * 16);
            }
#pragma unroll
            for (int mi = 0; mi < 4; ++mi)
#pragma unroll
                for (int ni = 0; ni < NR; ++ni)
                    acc[mi][ni] = __builtin_amdgcn_mfma_f32_16x16x32_bf16(
                        af[mi], bfv[ni], acc[mi][ni], 0, 0, 0);
        }
        cur ^= 1;
    }
    if constexpr (LP) {
        // epilogue + per-row partial logsumexp over this block's col slice
        __shared__ float pmx[2][128], psm[2][128];
        float bvv[NR];
#pragma unroll
        for (int ni = 0; ni < NR; ++ni) {
            long n = n0 + wc * (BN / 2) + ni * 16 + l15;
            bvv[ni] = (HAS_BIAS && n < N) ? bias[n] : 0.0f;
        }
#pragma unroll
        for (int mi = 0; mi < 4; ++mi) {
#pragma unroll
            for (int j = 0; j < 4; ++j) {
                long m = m0 + wr * 64 + mi * 16 + l4 * 4 + j;
                float vv[NR];
                float mx = -INFINITY;
#pragma unroll
                for (int ni = 0; ni < NR; ++ni) {
                    long n = n0 + wc * (BN / 2) + ni * 16 + l15;
                    float v = acc[mi][ni][j] + bvv[ni];
                    if (n < N) Cf[m * (long)ldc + n] = v;
                    else v = -INFINITY;
                    vv[ni] = v;
                    mx = fmaxf(mx, v);
                }
#pragma unroll
                for (int ofs = 1; ofs < 16; ofs <<= 1) mx = fmaxf(mx, __shfl_xor(mx, ofs));
                float sm = 0.f;
#pragma unroll
                for (int ni = 0; ni < NR; ++ni) sm += __expf(vv[ni] - mx);
#pragma unroll
                for (int ofs = 1; ofs < 16; ofs <<= 1) sm += __shfl_xor(sm, ofs);
                if (l15 == 0) {
                    int r2 = wr * 64 + mi * 16 + l4 * 4 + j;
                    pmx[wc][r2] = mx;
                    psm[wc][r2] = sm;
                }
            }
        }
        __syncthreads();
        if (tid < 128) {
            float m1 = pmx[0][tid], m2 = pmx[1][tid];
            float nm = fmaxf(m1, m2);
            float S = psm[0][tid] * __expf(m1 - nm) + psm[1][tid] * __expf(m2 - nm);
            part[(m0 + tid) * (long)ncb + bn] = make_float2(nm, S);
        }
    } else {
#pragma unroll
        for (int ni = 0; ni < NR; ++ni) {
            long n = n0 + wc * (BN / 2) + ni * 16 + l15;
            if (n < N) {
                float bv = HAS_BIAS ? bias[n] : 0.0f;
#pragma unroll
                for (int mi = 0; mi < 4; ++mi) {
#pragma unroll
                    for (int j = 0; j < 4; ++j) {
                        long m = m0 + wr * 64 + mi * 16 + l4 * 4 + j;
                        float v = acc[mi][ni][j] + bv;
                        if (HAS_RES) v += res[m * (long)ldc + n];
                        if (RELU) v = fmaxf(v, 0.0f);
                        if (OUT_BF16) Cb[m * (long)ldc + n] = f2bf(v);
                        else Cf[m * (long)ldc + n] = v;
                    }
                }
            }
        }
    }
}

// ---------------------------------------------------------------- MFMA attention
// block = (b,h); 4 waves, wave w owns q rows 32w..32w+31. qkv is bf16 [2048][3072].
__global__ __launch_bounds__(256) void k_attn_mfma(const u16* __restrict__ qkv,
                                                   u16* __restrict__ o) {
    __shared__ __align__(16) u16 Ks[128 * 64];       // row-chunks XOR-swizzled
    __shared__ __align__(16) u16 Vt[64 * 128];       // V transposed, swizzled
    __shared__ __align__(16) u16 Ps[4][32 * 128];    // per-wave P, swizzled
    int tid = threadIdx.x, lane = tid & 63, w = tid >> 6;
    int l15 = lane & 15, l4 = lane >> 4;
    int b = blockIdx.x >> 4, h = blockIdx.x & 15;
    const u16* base = qkv + (long)b * 128 * 3072 + h * 64;

    // K -> LDS via global_load_lds, pre-swizzled source (slot = chunk ^ (row&7))
    stage_tile<128>(base + 1024, 0, 127, 3072, 0, (char*)Ks, tid);

    // V -> LDS transposed: lane covers d=lane, gather 8 consecutive s, one b128 write
    {
        const u16* vg = base + 2048;
#pragma unroll
        for (int p = 0; p < 4; ++p) {
            int s0 = (w * 4 + p) * 8;
            u16 tmp[8];
#pragma unroll
            for (int j = 0; j < 8; ++j) tmp[j] = vg[(long)(s0 + j) * 3072 + lane];
            int slot = (s0 >> 3) ^ (lane & 7);
            *(bf16x8*)((char*)Vt + lane * 256 + slot * 16) = *(bf16x8*)tmp;
        }
    }
    // Q fragments direct from global
    bf16x8 aq[2][2];
#pragma unroll
    for (int mj = 0; mj < 2; ++mj)
#pragma unroll
        for (int kk = 0; kk < 2; ++kk)
            aq[mj][kk] = *(const bf16x8*)(base + (long)(w * 32 + mj * 16 + l15) * 3072 + kk * 32 + l4 * 8);
    __syncthreads();

    // S = Q K^T  (32 x 128 per wave)
    f32x4 sacc[2][8] = {};
#pragma unroll
    for (int sj = 0; sj < 8; ++sj) {
        bf16x8 bk[2];
#pragma unroll
        for (int kk = 0; kk < 2; ++kk) {
            int row = sj * 16 + l15;
            int slot = (kk * 4 + l4) ^ (row & 7);
            bk[kk] = *(const bf16x8*)((char*)Ks + (row * 8 + slot) * 16);
        }
#pragma unroll
        for (int mj = 0; mj < 2; ++mj) {
            sacc[mj][sj] = __builtin_amdgcn_mfma_f32_16x16x32_bf16(aq[mj][0], bk[0], sacc[mj][sj], 0, 0, 0);
            sacc[mj][sj] = __builtin_amdgcn_mfma_f32_16x16x32_bf16(aq[mj][1], bk[1], sacc[mj][sj], 0, 0, 0);
        }
    }
    // softmax rows (mask, scale by E^-0.5 = 1/32), write P (bf16) to LDS
    const float scale = 0.03125f;
#pragma unroll
    for (int mj = 0; mj < 2; ++mj) {
#pragma unroll
        for (int j = 0; j < 4; ++j) {
            int tq = w * 32 + mj * 16 + l4 * 4 + j;
            float mx = -INFINITY;
#pragma unroll
            for (int sj = 0; sj < 8; ++sj) {
                int s = sj * 16 + l15;
                float v = (s <= tq) ? sacc[mj][sj][j] * scale : -INFINITY;
                sacc[mj][sj][j] = v;
                mx = fmaxf(mx, v);
            }
#pragma unroll
            for (int ofs = 1; ofs < 16; ofs <<= 1) mx = fmaxf(mx, __shfl_xor(mx, ofs));
            float sm = 0.f;
#pragma unroll
            for (int sj = 0; sj < 8; ++sj) {
                float e = __expf(sacc[mj][sj][j] - mx);
                sacc[mj][sj][j] = e;
                sm += e;
            }
#pragma unroll
            for (int ofs = 1; ofs < 16; ofs <<= 1) sm += __shfl_xor(sm, ofs);
            float inv = 1.0f / sm;
            int m2 = mj * 16 + l4 * 4 + j;
            u16* prow = Ps[w] + m2 * 128;
#pragma unroll
            for (int sj = 0; sj < 8; ++sj) {
                int s = sj * 16 + l15;
                int slot = (s >> 3) ^ (m2 & 7);
                prow[slot * 8 + (s & 7)] = f2bf(sacc[mj][sj][j] * inv);
            }
        }
    }
    // O = P V   (32 x 64 per wave); P reads are wave-private (no barrier needed)
    f32x4 oacc[2][4] = {};
#pragma unroll
    for (int kk = 0; kk < 4; ++kk) {
        bf16x8 pa[2], bv[4];
#pragma unroll
        for (int mj = 0; mj < 2; ++mj) {
            int m2 = mj * 16 + l15;
            int slot = (kk * 4 + l4) ^ (m2 & 7);
            pa[mj] = *(const bf16x8*)((char*)(Ps[w]) + m2 * 256 + slot * 16);
        }
#pragma unroll
        for (int nb = 0; nb < 4; ++nb) {
            int d = nb * 16 + l15;
            int slot = (kk * 4 + l4) ^ (d & 7);
            bv[nb] = *(const bf16x8*)((char*)Vt + d * 256 + slot * 16);
        }
#pragma unroll
        for (int mj = 0; mj < 2; ++mj)
#pragma unroll
            for (int nb = 0; nb < 4; ++nb)
                oacc[mj][nb] = __builtin_amdgcn_mfma_f32_16x16x32_bf16(pa[mj], bv[nb], oacc[mj][nb], 0, 0, 0);
    }
#pragma unroll
    for (int mj = 0; mj < 2; ++mj)
#pragma unroll
        for (int nb = 0; nb < 4; ++nb) {
            int d = nb * 16 + l15;
#pragma unroll
            for (int j = 0; j < 4; ++j) {
                int tq = w * 32 + mj * 16 + l4 * 4 + j;
                o[((long)b * 128 + tq) * 1024 + h * 64 + d] = f2bf(oacc[mj][nb][j]);
            }
        }
}

// ---------------------------------------------------------------- loss from partials
__global__ __launch_bounds__(64) void k_loss_rows2(const float2* __restrict__ part,
                                                   const float* __restrict__ logits,
                                                   const int* __restrict__ tgt,
                                                   float* __restrict__ rowloss, int ncb) {
    int r = blockIdx.x, lane = threadIdx.x;
    float M = -INFINITY, S = 0.f;
    for (int cb = lane; cb < ncb; cb += 64) {
        float2 p = part[(long)r * ncb + cb];
        float nm = fmaxf(M, p.x);
        S = S * __expf(M - nm) + p.y * __expf(p.x - nm);
        M = nm;
    }
#pragma unroll
    for (int ofs = 32; ofs; ofs >>= 1) {
        float M2 = __shfl_xor(M, ofs), S2 = __shfl_xor(S, ofs);
        float nm = fmaxf(M, M2);
        S = S * __expf(M - nm) + S2 * __expf(M2 - nm);
        M = nm;
    }
    if (lane == 0)
        rowloss[r] = (M + logf(S)) - logits[(long)r * 50257 + tgt[r]];
}

__global__ __launch_bounds__(256) void k_loss_reduce(const float* __restrict__ rowloss,
                                                     float* __restrict__ out) {
    __shared__ float red[4];
    int tid = threadIdx.x, lane = tid & 63, wid = tid >> 6;
    float s = 0.f;
    for (int i = tid; i < 2048; i += 256) s += rowloss[i];
#pragma unroll
    for (int ofs = 32; ofs; ofs >>= 1) s += __shfl_xor(s, ofs);
    if (lane == 0) red[wid] = s;
    __syncthreads();
    if (tid == 0) out[0] = (red[0] + red[1] + red[2] + red[3]) * (1.0f / 2048.0f);
}

// ---------------------------------------------------------------- host
extern "C" void kernel_launch(void* const* d_in, const int* in_sizes, int n_in,
                              void* d_out, int out_size, void* d_ws, size_t ws_size,
                              hipStream_t stream) {
    (void)in_sizes; (void)n_in; (void)out_size; (void)ws_size;
    const int*   idx     = (const int*)d_in[0];
    const int*   targets = (const int*)d_in[1];
    const float* tok_emb = (const float*)d_in[2];
    const float* pos_emb = (const float*)d_in[3];
    const float* wq      = (const float*)d_in[4];
    const float* wk      = (const float*)d_in[5];
    const float* wv      = (const float*)d_in[6];
    const float* w_proj  = (const float*)d_in[7];
    const float* b_proj  = (const float*)d_in[8];
    const float* ln1_g   = (const float*)d_in[9];
    const float* ln1_b   = (const float*)d_in[10];
    const float* ln2_g   = (const float*)d_in[11];
    const float* ln2_b   = (const float*)d_in[12];
    const float* w_fc1   = (const float*)d_in[13];
    const float* b_fc1   = (const float*)d_in[14];
    const float* w_fc2   = (const float*)d_in[15];
    const float* b_fc2   = (const float*)d_in[16];
    const float* lnf_g   = (const float*)d_in[17];
    const float* lnf_b   = (const float*)d_in[18];
    const float* w_head  = (const float*)d_in[19];
    const float* b_head  = (const float*)d_in[20];
    float* out = (float*)d_out;

    char* w = (char*)d_ws;
    auto alloc = [&](size_t bytes) {
        char* p = w;
        w += (bytes + 255) & ~(size_t)255;
        return p;
    };
    u16*    wT_qkv  = (u16*)alloc(3072L * 1024 * 2);
    u16*    wT_proj = (u16*)alloc(1024L * 1024 * 2);
    u16*    wT_f1   = (u16*)alloc(4096L * 1024 * 2);
    u16*    wT_f2   = (u16*)alloc(1024L * 4096 * 2);
    u16*    wT_head = (u16*)alloc(50257L * 1024 * 2);
    float*  x       = (float*)alloc(2048L * 1024 * 4);
    u16*    h_bf    = (u16*)alloc(2048L * 1024 * 2);
    u16*    qkvb    = (u16*)alloc(2048L * 3072 * 2);
    u16*    o_bf    = (u16*)alloc(2048L * 1024 * 2);
    u16*    ff_bf   = (u16*)alloc(2048L * 4096 * 2);
    float2* part    = (float2*)alloc(2048L * 393 * 8);
    float*  rowloss = (float*)alloc(2048L * 4);

    k_embed<<<2048, 256, 0, stream>>>(idx, tok_emb, pos_emb, x);
    k_tr_one<<<dim3(786, 16), 256, 0, stream>>>(w_head, wT_head, 1024, 50257);

    for (int l = 0; l < 12; ++l) {
        k_tr_layer<<<3072, 256, 0, stream>>>(
            wq + (long)l * 1048576, wk + (long)l * 1048576,
            wv + (long)l * 1048576, w_proj + (long)l * 1048576,
            w_fc1 + (long)l * 4194304, w_fc2 + (long)l * 4194304,
            wT_qkv, wT_proj, wT_f1, wT_f2);
        k_ln<<<2048, 256, 0, stream>>>(x, ln1_g + l * 1024, ln1_b + l * 1024, h_bf);
        k_gemm<64, true, false, false, false, false, false><<<dim3(48, 16), 256, 0, stream>>>(
            h_bf, wT_qkv, nullptr, nullptr, nullptr, qkvb, 2048, 3072, 1024, 3072, nullptr, 0);
        k_attn_mfma<<<256, 256, 0, stream>>>(qkvb, o_bf);
        k_gemm<64, false, false, true, true, false, false><<<dim3(16, 16), 256, 0, stream>>>(
            o_bf, wT_proj, b_proj + l * 1024, x, x, nullptr, 2048, 1024, 1024, 1024, nullptr, 0);
        k_ln<<<2048, 256, 0, stream>>>(x, ln2_g + l * 1024, ln2_b + l * 1024, h_bf);
        k_gemm<128, true, true, true, false, false, false><<<dim3(32, 16), 256, 0, stream>>>(
            h_bf, wT_f1, b_fc1 + l * 4096, nullptr, nullptr, ff_bf, 2048, 4096, 1024, 4096, nullptr, 0);
        k_gemm<64, false, false, true, true, false, false><<<dim3(16, 16), 256, 0, stream>>>(
            ff_bf, wT_f2, b_fc2 + l * 1024, x, x, nullptr, 2048, 1024, 4096, 1024, nullptr, 0);
    }
    k_ln<<<2048, 256, 0, stream>>>(x, lnf_g, lnf_b, h_bf);
    k_gemm<128, false, false, true, false, true, true><<<dim3(16, 393), 256, 0, stream>>>(
        h_bf, wT_head, b_head, nullptr, out, nullptr, 2048, 50257, 1024, 50257, part, 393);
    k_loss_rows2<<<2048, 64, 0, stream>>>(part, out, targets, rowloss, 393);
    k_loss_reduce<<<1, 256, 0, stream>>>(rowloss, out + 102926336L);
}

// Round 4
// 2158.357 us; speedup vs baseline: 1.2223x; 1.0120x over previous
//
#include <hip/hip_runtime.h>
#include <math.h>

typedef unsigned short u16;
typedef float f32x4 __attribute__((ext_vector_type(4)));
typedef short bf16x8 __attribute__((ext_vector_type(8)));
typedef unsigned short us4 __attribute__((ext_vector_type(4)));

#define DEVI __device__ __forceinline__

DEVI float bf2f(u16 u) { return __uint_as_float(((unsigned int)u) << 16); }
DEVI u16 f2bf(float f) {
    unsigned int u = __float_as_uint(f);
    u += 0x7fffu + ((u >> 16) & 1u);
    return (u16)(u >> 16);
}

// ---------------------------------------------------------------- embedding
__global__ __launch_bounds__(256) void k_embed(const int* __restrict__ idx,
                                               const float* __restrict__ te,
                                               const float* __restrict__ pe,
                                               float* __restrict__ x) {
    int m = blockIdx.x;            // 0..2047
    int t = m & 127;
    int tok = idx[m];
    const f32x4* a = (const f32x4*)(te + (long)tok * 1024);
    const f32x4* p = (const f32x4*)(pe + (long)t * 1024);
    f32x4* o = (f32x4*)(x + (long)m * 1024);
    o[threadIdx.x] = a[threadIdx.x] + p[threadIdx.x];
}

// ---------------------------------------------------------------- layernorm -> bf16
__global__ __launch_bounds__(256) void k_ln(const float* __restrict__ x,
                                            const float* __restrict__ g,
                                            const float* __restrict__ b,
                                            u16* __restrict__ out) {
    __shared__ float red[8];
    int tid = threadIdx.x, lane = tid & 63, wid = tid >> 6;
    int r = blockIdx.x;
    f32x4 v = ((const f32x4*)(x + (long)r * 1024))[tid];
    float s = v.x + v.y + v.z + v.w;
#pragma unroll
    for (int o2 = 32; o2; o2 >>= 1) s += __shfl_xor(s, o2);
    if (lane == 0) red[wid] = s;
    __syncthreads();
    float mean = (red[0] + red[1] + red[2] + red[3]) * (1.0f / 1024.0f);
    f32x4 d; d.x = v.x - mean; d.y = v.y - mean; d.z = v.z - mean; d.w = v.w - mean;
    float sq = d.x * d.x + d.y * d.y + d.z * d.z + d.w * d.w;
#pragma unroll
    for (int o2 = 32; o2; o2 >>= 1) sq += __shfl_xor(sq, o2);
    if (lane == 0) red[4 + wid] = sq;
    __syncthreads();
    float rstd = rsqrtf((red[4] + red[5] + red[6] + red[7]) * (1.0f / 1024.0f) + 1e-5f);
    f32x4 gg = ((const f32x4*)g)[tid];
    f32x4 bb = ((const f32x4*)b)[tid];
    us4 o4;
    o4.x = f2bf(d.x * rstd * gg.x + bb.x);
    o4.y = f2bf(d.y * rstd * gg.y + bb.y);
    o4.z = f2bf(d.z * rstd * gg.z + bb.z);
    o4.w = f2bf(d.w * rstd * gg.w + bb.w);
    ((us4*)(out + (long)r * 1024))[tid] = o4;
}

// ---------------------------------------------------------------- transpose + cvt f32[K][N] -> bf16[N][K]
DEVI void tr_tile(const float* __restrict__ in, u16* __restrict__ out,
                  int K, int N, int k0, int n0, int tid, float (*tile)[65]) {
    int trow = tid >> 4;             // 0..15
    int tcol = (tid & 15) * 4;       // 0..60
#pragma unroll
    for (int p = 0; p < 4; ++p) {
        int k = k0 + trow + p * 16;
        const float* src = in + (long)k * N + n0 + tcol;
#pragma unroll
        for (int j = 0; j < 4; ++j) {
            int n = n0 + tcol + j;
            tile[trow + p * 16][tcol + j] = (n < N) ? src[j] : 0.0f;
        }
    }
    __syncthreads();
#pragma unroll
    for (int p = 0; p < 4; ++p) {
        int n = n0 + trow + p * 16;
        if (n < N) {
            us4 o4;
#pragma unroll
            for (int j = 0; j < 4; ++j) o4[j] = f2bf(tile[tcol + j][trow + p * 16]);
            *(us4*)(out + (long)n * K + k0 + tcol) = o4;
        }
    }
}

__global__ __launch_bounds__(256) void k_tr_one(const float* __restrict__ in,
                                                u16* __restrict__ out, int K, int N) {
    __shared__ float tile[64][65];
    tr_tile(in, out, K, N, blockIdx.y * 64, blockIdx.x * 64, threadIdx.x, tile);
}

__global__ __launch_bounds__(256) void k_tr_layer(
    const float* __restrict__ wq, const float* __restrict__ wk,
    const float* __restrict__ wv, const float* __restrict__ wp,
    const float* __restrict__ f1, const float* __restrict__ f2,
    u16* __restrict__ oqkv, u16* __restrict__ oproj,
    u16* __restrict__ of1, u16* __restrict__ of2) {
    __shared__ float tile[64][65];
    int id = blockIdx.x;
    const float* in; u16* out; int K, N, txx, tyy;
    if (id < 1024) {
        int t = id >> 8, s2 = id & 255;
        txx = s2 & 15; tyy = s2 >> 4; K = 1024; N = 1024;
        in = (t == 0) ? wq : (t == 1) ? wk : (t == 2) ? wv : wp;
        out = (t == 3) ? oproj : oqkv + (long)t * 1024 * 1024;
    } else if (id < 2048) {
        int s2 = id - 1024;
        txx = s2 & 63; tyy = s2 >> 6; K = 1024; N = 4096; in = f1; out = of1;
    } else {
        int s2 = id - 2048;
        txx = s2 & 15; tyy = s2 >> 4; K = 4096; N = 1024; in = f2; out = of2;
    }
    tr_tile(in, out, K, N, tyy * 64, txx * 64, threadIdx.x, tile);
}

// ---------------------------------------------------------------- staging helpers (XOR-swizzled, global_load_lds 16B)
template <int ROWS>
DEVI void stage_tile(const u16* __restrict__ g, long row0, long rowmax, int ld,
                     int col0, char* lds, int tid) {
    constexpr int NCH = ROWS * 8;
#pragma unroll
    for (int p = 0; p < NCH / 256; ++p) {
        int c = tid + p * 256;
        int row = c >> 3;
        int gslot = c & 7;
        int gdata = gslot ^ (row & 7);
        long gr = row0 + row;
        if (gr > rowmax) gr = rowmax;
        const u16* src = g + gr * (long)ld + col0 + gdata * 8;
        char* dst = lds + ((long)((tid & 192) + p * 256)) * 16;
        __builtin_amdgcn_global_load_lds(
            (const __attribute__((address_space(1))) void*)src,
            (__attribute__((address_space(3))) void*)dst, 16, 0, 0);
    }
}

// 512-thread variant: ROWS x 64 bf16 tile, 16B chunks, slot ^= row&7
template <int ROWS>
DEVI void stage512(const u16* __restrict__ g, long row0, long rowmax, int ld,
                   int col0, char* lds, int tid) {
    constexpr int NP = ROWS * 8 / 512;     // 4 for ROWS=256
#pragma unroll
    for (int p = 0; p < NP; ++p) {
        int c = tid + p * 512;
        int row = c >> 3;
        int gslot = c & 7;
        int gdata = gslot ^ (row & 7);
        long gr = row0 + row;
        if (gr > rowmax) gr = rowmax;
        const u16* src = g + gr * (long)ld + col0 + gdata * 8;
        char* dst = lds + ((long)((tid & 448) + p * 512)) * 16;
        __builtin_amdgcn_global_load_lds(
            (const __attribute__((address_space(1))) void*)src,
            (__attribute__((address_space(3))) void*)dst, 16, 0, 0);
    }
}

// ---------------------------------------------------------------- per-layer GEMM (128 x BN, 2-barrier m97 structure)
template <int BN, bool OUT_BF16, bool RELU, bool HAS_BIAS, bool HAS_RES>
__global__ __launch_bounds__(256, 2) void k_gemm(
    const u16* __restrict__ A, const u16* __restrict__ Bt,
    const float* __restrict__ bias, const float* __restrict__ res,
    float* __restrict__ Cf, u16* __restrict__ Cb,
    int M, int N, int K, int ldc) {
    constexpr int NR = BN / 32;
    constexpr int ASZ = 128 * 64 * 2;
    constexpr int BSZ = BN * 64 * 2;
    __shared__ __align__(16) char lds[2 * (ASZ + BSZ)];
    int tid = threadIdx.x, lane = tid & 63, wid = tid >> 6;
    int l15 = lane & 15, l4 = lane >> 4;
    int wr = wid >> 1, wc = wid & 1;
    long m0 = (long)blockIdx.y * 128;
    long n0 = (long)blockIdx.x * BN;
    f32x4 acc[4][NR] = {};
    const int nk = K >> 6;

    stage_tile<128>(A, m0, (long)M - 1, K, 0, lds, tid);
    stage_tile<BN>(Bt, n0, (long)N - 1, K, 0, lds + ASZ, tid);
    int cur = 0;
    for (int kt = 0; kt < nk; ++kt) {
        __syncthreads();
        if (kt + 1 < nk) {
            char* nb = lds + (cur ^ 1) * (ASZ + BSZ);
            stage_tile<128>(A, m0, (long)M - 1, K, (kt + 1) << 6, nb, tid);
            stage_tile<BN>(Bt, n0, (long)N - 1, K, (kt + 1) << 6, nb + ASZ, tid);
        }
        const char* ab = lds + cur * (ASZ + BSZ);
        const char* bb = ab + ASZ;
#pragma unroll
        for (int kh = 0; kh < 2; ++kh) {
            bf16x8 af[4], bfv[NR];
#pragma unroll
            for (int mi = 0; mi < 4; ++mi) {
                int row = wr * 64 + mi * 16 + l15;
                int slot = (kh * 4 + l4) ^ (row & 7);
                af[mi] = *(const bf16x8*)(ab + (row * 8 + slot) * 16);
            }
#pragma unroll
            for (int ni = 0; ni < NR; ++ni) {
                int row = wc * (BN / 2) + ni * 16 + l15;
                int slot = (kh * 4 + l4) ^ (row & 7);
                bfv[ni] = *(const bf16x8*)(bb + (row * 8 + slot) * 16);
            }
#pragma unroll
            for (int mi = 0; mi < 4; ++mi)
#pragma unroll
                for (int ni = 0; ni < NR; ++ni)
                    acc[mi][ni] = __builtin_amdgcn_mfma_f32_16x16x32_bf16(
                        af[mi], bfv[ni], acc[mi][ni], 0, 0, 0);
        }
        cur ^= 1;
    }
#pragma unroll
    for (int ni = 0; ni < NR; ++ni) {
        long n = n0 + wc * (BN / 2) + ni * 16 + l15;
        if (n < N) {
            float bv = HAS_BIAS ? bias[n] : 0.0f;
#pragma unroll
            for (int mi = 0; mi < 4; ++mi) {
#pragma unroll
                for (int j = 0; j < 4; ++j) {
                    long m = m0 + wr * 64 + mi * 16 + l4 * 4 + j;
                    float v = acc[mi][ni][j] + bv;
                    if (HAS_RES) v += res[m * (long)ldc + n];
                    if (RELU) v = fmaxf(v, 0.0f);
                    if (OUT_BF16) Cb[m * (long)ldc + n] = f2bf(v);
                    else Cf[m * (long)ldc + n] = v;
                }
            }
        }
    }
}

// ---------------------------------------------------------------- head GEMM: 256x256 tile, counted-vmcnt pipeline,
// fused logits store + per-(row, col-block) partial logsumexp.
// Invalid (n >= N) columns use a large FINITE sentinel (-1e30f): an all-invalid
// 64-col wave slice then yields mx=-1e30, sm finite, and contributes exactly 0
// after the exp(m2 - nm) merge — no exp(-inf - -inf) = NaN path (round-3 bug).
__global__ __launch_bounds__(512, 2) void k_gemm_head(
    const u16* __restrict__ A, const u16* __restrict__ Bt,
    const float* __restrict__ bias, float* __restrict__ Cf,
    float2* __restrict__ part, int M, int N, int K, int ldc, int ncb) {
    constexpr int TSZ = 256 * 64 * 2;            // 32 KB per matrix per buffer
    __shared__ __align__(16) char lds[4 * TSZ];  // buf0{A,B}, buf1{A,B} = 128 KB
    __shared__ float pmx[4][256], psm[4][256];
    int tid = threadIdx.x, lane = tid & 63, wid = tid >> 6;
    int l15 = lane & 15, l4 = lane >> 4;
    int wr = wid >> 2, wc = wid & 3;             // 2 x 4 wave grid; wave owns 128 x 64
    int bm = blockIdx.x & 7, bn = blockIdx.x >> 3;   // bm-fastest: 8 bm share a B panel
    long m0 = (long)bm * 256, n0 = (long)bn * 256;
    const int nk = K >> 6;                       // 16
    f32x4 acc[8][4] = {};

    // prologue: stage tiles 0 and 1 (8 loads/thread each)
    stage512<256>(A, m0, (long)M - 1, K, 0, lds, tid);
    stage512<256>(Bt, n0, (long)N - 1, K, 0, lds + TSZ, tid);
    stage512<256>(A, m0, (long)M - 1, K, 64, lds + 2 * TSZ, tid);
    stage512<256>(Bt, n0, (long)N - 1, K, 64, lds + 3 * TSZ, tid);

    for (int t = 0; t < nk; ++t) {
        if (t < nk - 1) asm volatile("s_waitcnt vmcnt(8)" ::: "memory");  // tile t landed; t+1 in flight
        else            asm volatile("s_waitcnt vmcnt(0)" ::: "memory");
        __builtin_amdgcn_s_barrier();            // all waves' tile-t chunks landed
        const char* ab = lds + (t & 1) * 2 * TSZ;
        const char* bb = ab + TSZ;
#pragma unroll
        for (int kh = 0; kh < 2; ++kh) {
            bf16x8 af[8], bfv[4];
#pragma unroll
            for (int mi = 0; mi < 8; ++mi) {
                int row = wr * 128 + mi * 16 + l15;
                int slot = (kh * 4 + l4) ^ (row & 7);
                af[mi] = *(const bf16x8*)(ab + (row * 8 + slot) * 16);
            }
#pragma unroll
            for (int ni = 0; ni < 4; ++ni) {
                int row = wc * 64 + ni * 16 + l15;
                int slot = (kh * 4 + l4) ^ (row & 7);
                bfv[ni] = *(const bf16x8*)(bb + (row * 8 + slot) * 16);
            }
            __builtin_amdgcn_s_setprio(1);
#pragma unroll
            for (int mi = 0; mi < 8; ++mi)
#pragma unroll
                for (int ni = 0; ni < 4; ++ni)
                    acc[mi][ni] = __builtin_amdgcn_mfma_f32_16x16x32_bf16(
                        af[mi], bfv[ni], acc[mi][ni], 0, 0, 0);
            __builtin_amdgcn_s_setprio(0);
        }
        __builtin_amdgcn_s_barrier();            // all waves done reading buf[t&1]
        if (t + 2 < nk) {                        // refill just-freed buffer; stays in flight across next K-step
            char* na = lds + (t & 1) * 2 * TSZ;
            stage512<256>(A, m0, (long)M - 1, K, (t + 2) << 6, na, tid);
            stage512<256>(Bt, n0, (long)N - 1, K, (t + 2) << 6, na + TSZ, tid);
        }
    }
    // epilogue: logits store + partial LSE over this block's 256-col slice
    const float BIG_NEG = -1e30f;
    float bvv[4];
#pragma unroll
    for (int ni = 0; ni < 4; ++ni) {
        long n = n0 + wc * 64 + ni * 16 + l15;
        bvv[ni] = (n < N) ? bias[n] : 0.0f;
    }
#pragma unroll
    for (int mi = 0; mi < 8; ++mi) {
#pragma unroll
        for (int j = 0; j < 4; ++j) {
            int rloc = wr * 128 + mi * 16 + l4 * 4 + j;
            long m = m0 + rloc;
            float mx = BIG_NEG, vv[4];
#pragma unroll
            for (int ni = 0; ni < 4; ++ni) {
                long n = n0 + wc * 64 + ni * 16 + l15;
                float v = acc[mi][ni][j] + bvv[ni];
                if (n < N) Cf[m * (long)ldc + n] = v;
                else v = BIG_NEG;
                vv[ni] = v;
                mx = fmaxf(mx, v);
            }
#pragma unroll
            for (int ofs = 1; ofs < 16; ofs <<= 1) mx = fmaxf(mx, __shfl_xor(mx, ofs));
            float sm = 0.f;
#pragma unroll
            for (int ni = 0; ni < 4; ++ni) sm += __expf(vv[ni] - mx);
#pragma unroll
            for (int ofs = 1; ofs < 16; ofs <<= 1) sm += __shfl_xor(sm, ofs);
            if (l15 == 0) { pmx[wc][rloc] = mx; psm[wc][rloc] = sm; }
        }
    }
    __syncthreads();
    if (tid < 256) {
        // wc=0 slice of every block is fully valid (50176+64 <= 50257), so Mv stays finite.
        float Mv = pmx[0][tid], Sv = psm[0][tid];
#pragma unroll
        for (int q = 1; q < 4; ++q) {
            float m2 = pmx[q][tid], s2 = psm[q][tid];
            float nm = fmaxf(Mv, m2);
            Sv = Sv * __expf(Mv - nm) + s2 * __expf(m2 - nm);
            Mv = nm;
        }
        part[(m0 + tid) * (long)ncb + bn] = make_float2(Mv, Sv);
    }
}

// ---------------------------------------------------------------- MFMA attention
__global__ __launch_bounds__(256) void k_attn_mfma(const u16* __restrict__ qkv,
                                                   u16* __restrict__ o) {
    __shared__ __align__(16) u16 Ks[128 * 64];
    __shared__ __align__(16) u16 Vt[64 * 128];
    __shared__ __align__(16) u16 Ps[4][32 * 128];
    int tid = threadIdx.x, lane = tid & 63, w = tid >> 6;
    int l15 = lane & 15, l4 = lane >> 4;
    int b = blockIdx.x >> 4, h = blockIdx.x & 15;
    const u16* base = qkv + (long)b * 128 * 3072 + h * 64;

    stage_tile<128>(base + 1024, 0, 127, 3072, 0, (char*)Ks, tid);
    {
        const u16* vg = base + 2048;
#pragma unroll
        for (int p = 0; p < 4; ++p) {
            int s0 = (w * 4 + p) * 8;
            u16 tmp[8];
#pragma unroll
            for (int j = 0; j < 8; ++j) tmp[j] = vg[(long)(s0 + j) * 3072 + lane];
            int slot = (s0 >> 3) ^ (lane & 7);
            *(bf16x8*)((char*)Vt + lane * 256 + slot * 16) = *(bf16x8*)tmp;
        }
    }
    bf16x8 aq[2][2];
#pragma unroll
    for (int mj = 0; mj < 2; ++mj)
#pragma unroll
        for (int kk = 0; kk < 2; ++kk)
            aq[mj][kk] = *(const bf16x8*)(base + (long)(w * 32 + mj * 16 + l15) * 3072 + kk * 32 + l4 * 8);
    __syncthreads();

    f32x4 sacc[2][8] = {};
#pragma unroll
    for (int sj = 0; sj < 8; ++sj) {
        bf16x8 bk[2];
#pragma unroll
        for (int kk = 0; kk < 2; ++kk) {
            int row = sj * 16 + l15;
            int slot = (kk * 4 + l4) ^ (row & 7);
            bk[kk] = *(const bf16x8*)((char*)Ks + (row * 8 + slot) * 16);
        }
#pragma unroll
        for (int mj = 0; mj < 2; ++mj) {
            sacc[mj][sj] = __builtin_amdgcn_mfma_f32_16x16x32_bf16(aq[mj][0], bk[0], sacc[mj][sj], 0, 0, 0);
            sacc[mj][sj] = __builtin_amdgcn_mfma_f32_16x16x32_bf16(aq[mj][1], bk[1], sacc[mj][sj], 0, 0, 0);
        }
    }
    const float scale = 0.03125f;
#pragma unroll
    for (int mj = 0; mj < 2; ++mj) {
#pragma unroll
        for (int j = 0; j < 4; ++j) {
            int tq = w * 32 + mj * 16 + l4 * 4 + j;
            float mx = -INFINITY;
#pragma unroll
            for (int sj = 0; sj < 8; ++sj) {
                int s = sj * 16 + l15;
                float v = (s <= tq) ? sacc[mj][sj][j] * scale : -INFINITY;
                sacc[mj][sj][j] = v;
                mx = fmaxf(mx, v);
            }
#pragma unroll
            for (int ofs = 1; ofs < 16; ofs <<= 1) mx = fmaxf(mx, __shfl_xor(mx, ofs));
            float sm = 0.f;
#pragma unroll
            for (int sj = 0; sj < 8; ++sj) {
                float e = __expf(sacc[mj][sj][j] - mx);
                sacc[mj][sj][j] = e;
                sm += e;
            }
#pragma unroll
            for (int ofs = 1; ofs < 16; ofs <<= 1) sm += __shfl_xor(sm, ofs);
            float inv = 1.0f / sm;
            int m2 = mj * 16 + l4 * 4 + j;
            u16* prow = Ps[w] + m2 * 128;
#pragma unroll
            for (int sj = 0; sj < 8; ++sj) {
                int s = sj * 16 + l15;
                int slot = (s >> 3) ^ (m2 & 7);
                prow[slot * 8 + (s & 7)] = f2bf(sacc[mj][sj][j] * inv);
            }
        }
    }
    f32x4 oacc[2][4] = {};
#pragma unroll
    for (int kk = 0; kk < 4; ++kk) {
        bf16x8 pa[2], bv[4];
#pragma unroll
        for (int mj = 0; mj < 2; ++mj) {
            int m2 = mj * 16 + l15;
            int slot = (kk * 4 + l4) ^ (m2 & 7);
            pa[mj] = *(const bf16x8*)((char*)(Ps[w]) + m2 * 256 + slot * 16);
        }
#pragma unroll
        for (int nb = 0; nb < 4; ++nb) {
            int d = nb * 16 + l15;
            int slot = (kk * 4 + l4) ^ (d & 7);
            bv[nb] = *(const bf16x8*)((char*)Vt + d * 256 + slot * 16);
        }
#pragma unroll
        for (int mj = 0; mj < 2; ++mj)
#pragma unroll
            for (int nb = 0; nb < 4; ++nb)
                oacc[mj][nb] = __builtin_amdgcn_mfma_f32_16x16x32_bf16(pa[mj], bv[nb], oacc[mj][nb], 0, 0, 0);
    }
#pragma unroll
    for (int mj = 0; mj < 2; ++mj)
#pragma unroll
        for (int nb = 0; nb < 4; ++nb) {
            int d = nb * 16 + l15;
#pragma unroll
            for (int j = 0; j < 4; ++j) {
                int tq = w * 32 + mj * 16 + l4 * 4 + j;
                o[((long)b * 128 + tq) * 1024 + h * 64 + d] = f2bf(oacc[mj][nb][j]);
            }
        }
}

// ---------------------------------------------------------------- loss from partials
__global__ __launch_bounds__(64) void k_loss_rows2(const float2* __restrict__ part,
                                                   const float* __restrict__ logits,
                                                   const int* __restrict__ tgt,
                                                   float* __restrict__ rowloss, int ncb) {
    int r = blockIdx.x, lane = threadIdx.x;
    float M = -1e30f, S = 0.f;
    for (int cb = lane; cb < ncb; cb += 64) {
        float2 p = part[(long)r * ncb + cb];
        float nm = fmaxf(M, p.x);
        S = S * __expf(M - nm) + p.y * __expf(p.x - nm);
        M = nm;
    }
#pragma unroll
    for (int ofs = 32; ofs; ofs >>= 1) {
        float M2 = __shfl_xor(M, ofs), S2 = __shfl_xor(S, ofs);
        float nm = fmaxf(M, M2);
        S = S * __expf(M - nm) + S2 * __expf(M2 - nm);
        M = nm;
    }
    if (lane == 0)
        rowloss[r] = (M + logf(S)) - logits[(long)r * 50257 + tgt[r]];
}

__global__ __launch_bounds__(256) void k_loss_reduce(const float* __restrict__ rowloss,
                                                     float* __restrict__ out) {
    __shared__ float red[4];
    int tid = threadIdx.x, lane = tid & 63, wid = tid >> 6;
    float s = 0.f;
    for (int i = tid; i < 2048; i += 256) s += rowloss[i];
#pragma unroll
    for (int ofs = 32; ofs; ofs >>= 1) s += __shfl_xor(s, ofs);
    if (lane == 0) red[wid] = s;
    __syncthreads();
    if (tid == 0) out[0] = (red[0] + red[1] + red[2] + red[3]) * (1.0f / 2048.0f);
}

// ---------------------------------------------------------------- host
extern "C" void kernel_launch(void* const* d_in, const int* in_sizes, int n_in,
                              void* d_out, int out_size, void* d_ws, size_t ws_size,
                              hipStream_t stream) {
    (void)in_sizes; (void)n_in; (void)out_size; (void)ws_size;
    const int*   idx     = (const int*)d_in[0];
    const int*   targets = (const int*)d_in[1];
    const float* tok_emb = (const float*)d_in[2];
    const float* pos_emb = (const float*)d_in[3];
    const float* wq      = (const float*)d_in[4];
    const float* wk      = (const float*)d_in[5];
    const float* wv      = (const float*)d_in[6];
    const float* w_proj  = (const float*)d_in[7];
    const float* b_proj  = (const float*)d_in[8];
    const float* ln1_g   = (const float*)d_in[9];
    const float* ln1_b   = (const float*)d_in[10];
    const float* ln2_g   = (const float*)d_in[11];
    const float* ln2_b   = (const float*)d_in[12];
    const float* w_fc1   = (const float*)d_in[13];
    const float* b_fc1   = (const float*)d_in[14];
    const float* w_fc2   = (const float*)d_in[15];
    const float* b_fc2   = (const float*)d_in[16];
    const float* lnf_g   = (const float*)d_in[17];
    const float* lnf_b   = (const float*)d_in[18];
    const float* w_head  = (const float*)d_in[19];
    const float* b_head  = (const float*)d_in[20];
    float* out = (float*)d_out;

    char* w = (char*)d_ws;
    auto alloc = [&](size_t bytes) {
        char* p = w;
        w += (bytes + 255) & ~(size_t)255;
        return p;
    };
    u16*    wT_qkv  = (u16*)alloc(3072L * 1024 * 2);
    u16*    wT_proj = (u16*)alloc(1024L * 1024 * 2);
    u16*    wT_f1   = (u16*)alloc(4096L * 1024 * 2);
    u16*    wT_f2   = (u16*)alloc(1024L * 4096 * 2);
    u16*    wT_head = (u16*)alloc(50257L * 1024 * 2);
    float*  x       = (float*)alloc(2048L * 1024 * 4);
    u16*    h_bf    = (u16*)alloc(2048L * 1024 * 2);
    u16*    qkvb    = (u16*)alloc(2048L * 3072 * 2);
    u16*    o_bf    = (u16*)alloc(2048L * 1024 * 2);
    u16*    ff_bf   = (u16*)alloc(2048L * 4096 * 2);
    float2* part    = (float2*)alloc(2048L * 197 * 8);
    float*  rowloss = (float*)alloc(2048L * 4);

    k_embed<<<2048, 256, 0, stream>>>(idx, tok_emb, pos_emb, x);
    k_tr_one<<<dim3(786, 16), 256, 0, stream>>>(w_head, wT_head, 1024, 50257);

    for (int l = 0; l < 12; ++l) {
        k_tr_layer<<<3072, 256, 0, stream>>>(
            wq + (long)l * 1048576, wk + (long)l * 1048576,
            wv + (long)l * 1048576, w_proj + (long)l * 1048576,
            w_fc1 + (long)l * 4194304, w_fc2 + (long)l * 4194304,
            wT_qkv, wT_proj, wT_f1, wT_f2);
        k_ln<<<2048, 256, 0, stream>>>(x, ln1_g + l * 1024, ln1_b + l * 1024, h_bf);
        k_gemm<64, true, false, false, false><<<dim3(48, 16), 256, 0, stream>>>(
            h_bf, wT_qkv, nullptr, nullptr, nullptr, qkvb, 2048, 3072, 1024, 3072);
        k_attn_mfma<<<256, 256, 0, stream>>>(qkvb, o_bf);
        k_gemm<64, false, false, true, true><<<dim3(16, 16), 256, 0, stream>>>(
            o_bf, wT_proj, b_proj + l * 1024, x, x, nullptr, 2048, 1024, 1024, 1024);
        k_ln<<<2048, 256, 0, stream>>>(x, ln2_g + l * 1024, ln2_b + l * 1024, h_bf);
        k_gemm<128, true, true, true, false><<<dim3(32, 16), 256, 0, stream>>>(
            h_bf, wT_f1, b_fc1 + l * 4096, nullptr, nullptr, ff_bf, 2048, 4096, 1024, 4096);
        k_gemm<64, false, false, true, true><<<dim3(16, 16), 256, 0, stream>>>(
            ff_bf, wT_f2, b_fc2 + l * 1024, x, x, nullptr, 2048, 1024, 4096, 1024);
    }
    k_ln<<<2048, 256, 0, stream>>>(x, lnf_g, lnf_b, h_bf);
    k_gemm_head<<<1576, 512, 0, stream>>>(h_bf, wT_head, b_head, out, part,
                                          2048, 50257, 1024, 50257, 197);
    k_loss_rows2<<<2048, 64, 0, stream>>>(part, out, targets, rowloss, 197);
    k_loss_reduce<<<1, 256, 0, stream>>>(rowloss, out + 102926336L);
}